// Round 1
// 258.669 us; speedup vs baseline: 1.1368x; 1.1368x over previous
//
#include <hip/hip_runtime.h>
#include <stdint.h>

static constexpr int kN = 128;
static constexpr int kTri = (kN * (kN - 1)) / 2;   // 8128 (BT scratch indexing)
static constexpr int kTriD = (kN * (kN + 1)) / 2;  // 8256 cells incl. diagonal
static constexpr int kThreads = 1024;
static constexpr float kNeg = -9999.0f;
static constexpr float kThresh = -9000.0f;
static constexpr float kArcBonus = 5.0f;
static constexpr int kDynLds = kTriD * 16;  // 132,096 B (one float4 quad per cell)
static constexpr int kCMax = 9;             // max row-cache slots per lane

__device__ __forceinline__ int rowBase(int i) { return (i * (2 * kN - 1 - i)) / 2; }
__device__ __forceinline__ int colBaseD(int c) { return (c * (c + 1)) / 2; }  // cells (r<=c, c)

// LDS-only workgroup barrier: orders LDS without draining vmcnt (wsBT stores
// and vL/vR prefetch loads stay in flight across steps).
__device__ __forceinline__ void ldsBarrier() {
    asm volatile("s_waitcnt lgkmcnt(0)\n\ts_barrier" ::: "memory");
}

template <int CTRL>
__device__ __forceinline__ float dppMax(float x) {
    const int y = __builtin_amdgcn_update_dpp(__float_as_int(x), __float_as_int(x),
                                              CTRL, 0xF, 0xF, true);
    return fmaxf(x, __int_as_float(y));
}
__device__ __forceinline__ float swzMax16(float x) {  // xor-16 within 32 lanes
    const int y = __builtin_amdgcn_ds_swizzle(__float_as_int(x), 0x401F);
    return fmaxf(x, __int_as_float(y));
}

// Static phase schedule (kN=128, 1024 threads): serial k<=16; P=8 k in [17,63];
// P=16 [64,95]; P=32 [96,111]; P=64 [112,127].
__device__ __forceinline__ int lpOf(int k) {
    if (k <= 16) return 0;
    if (k < 64) return 3;
    if (k < 96) return 4;
    if (k < 112) return 5;
    return 6;
}
__device__ __forceinline__ void mapStatic(int nk, int tid, int& i, int& j, bool& act) {
    const int lp = lpOf(nk);
    i = tid >> lp;
    j = i + nk;
    act = i < (kN - nk);
}

// Quad per cell: {x=s00, y=s11, z=s01, w=s10}, col-major incl. diagonal (diag=0).
// Serial-phase scan (unchanged): both row and column quads from LDS.
__device__ __forceinline__ void scanChunk(const float4* __restrict__ Q4,
                                          int i, int j, int k, int mlo, int mhi,
                                          float vL,
                                          float& bmax, int& ib,
                                          float& v01, int& i01,
                                          float& v11, int& i11) {
    const int qjb = colBaseD(j);  // + r => cell (r, j)
    int q, mstart;
    float4 cur;
    if (mlo == 0) {
        q = i + 1;
        cur = Q4[qjb + q];  // quad(i+1, j); diagonal zeros when k==1
        bmax = cur.z; ib = 0;   // base(0) = 0 + s01[i+1][j]
        const float p00 = (cur.z + vL) + kArcBonus;
        v01 = (p00 > kThresh) ? p00 : kNeg; i01 = 0;  // part00 seed
        mstart = 1;
    } else {
        q = i + mlo;
        cur = Q4[qjb + q];
        mstart = mlo;
    }
    int dA = colBaseD(q) + i;  // cell (i, q)
    int dInc = q + 1;          // colBaseD(q+1) - colBaseD(q)
#pragma unroll 8
    for (int m = mstart; m < mhi; ++m) {
        const float4 nxt = Q4[qjb + q + 1];  // quad(q+1, j); diag zeros at m==k-1
        const float4 diq = Q4[dA];           // quad(i, q)
        const float base = diq.y + nxt.z;    // s11[i][q] + s01[q+1][j]
        const float p01 = diq.z + cur.x;     // s01[i][q] + s00[q][j]
        const float p11 = diq.w + cur.y;     // s10[i][q] + s11[q][j]
        if (base > bmax) { bmax = base; ib = m; }  // strict > keeps earliest m
        if (p01 > v01) { v01 = p01; i01 = m; }
        if (p11 > v11) { v11 = p11; i11 = m; }
        cur = nxt;
        dA += dInc; ++dInc;
        ++q;
    }
}

__device__ __forceinline__ void writeCell(float4* __restrict__ Q4,
                                          uint32_t* __restrict__ wsBT,
                                          int i, int j, int k,
                                          float gb, int ib, float vLc, float vRc,
                                          float v01, int i01, float v11, int i11) {
    const float v00 = (gb + vLc) + kArcBonus;
    const float v10 = (gb + vRc) + kArcBonus;
    const float new10 = (v10 > kThresh) ? v10 : kNeg;
    if (new10 > v11) { v11 = new10; i11 = k; }  // q=j candidate; strict > keeps earlier q
    float4 w = make_float4(kNeg, kNeg, kNeg, kNeg);
    uint32_t p = 0;
    if (v00 > kThresh) { w.x = v00; p |= (uint32_t)(i + ib); }
    if (v01 > kThresh) { w.z = v01; p |= (uint32_t)(i + i01) << 8; }
    if (v10 > kThresh) { w.w = v10; p |= (uint32_t)(i + ib) << 16; }
    if (v11 > kThresh) { w.y = v11; p |= (uint32_t)(i + i11) << 24; }
    Q4[colBaseD(j) + i] = w;          // one ds_write_b128
    wsBT[rowBase(i) + k - 1] = p;     // lone global store; not drained per step
}

// Serial step (k<=16): one thread per cell, exactly the old LP=0 path.
__device__ __forceinline__ void doStepSerial(int k, int tid,
                                             float4* __restrict__ Q4,
                                             uint32_t* __restrict__ wsBT,
                                             const float* __restrict__ v,
                                             int& ci, int& cj, bool& cact,
                                             float& vL, float& vR) {
    const int i = ci, j = cj;
    const bool act = cact;
    const float vLc = vL, vRc = vR;
    float bmax = -3.0e38f, v01 = -3.0e38f, v11 = -3.0e38f;
    int ib = 0, i01 = 0, i11 = 0x7FFFFFFF;
    if (act) {
        scanChunk(Q4, i, j, k, 0, k, vLc, bmax, ib, v01, i01, v11, i11);
    }
    if (k + 1 < kN) {
        mapStatic(k + 1, tid, ci, cj, cact);
        vL = cact ? v[cj * kN + ci] : 0.f;
        vR = cact ? v[ci * kN + cj] : 0.f;
    }
    if (act) {
        writeCell(Q4, wsBT, i, j, k, bmax, ib, vLc, vRc, v01, i01, v11, i11);
    }
}

// ---- Row-cache machinery for chunked phases ----
// Within a phase, i = tid>>LP is FIXED and chart cells are write-once, so the
// row operands {s11,s01,s10}(i, i+m) for this lane's fixed m-chunk are loaded
// once (preload) + one fresh quad per step (the cell written last step), and
// then live in registers. Only the column stream (j advances with k) re-reads
// LDS; fixed ODD chunk stride C keeps it bank-conflict-free and gives the
// ds_reads compile-time offset immediates. Slot c <-> m = mstart + c.
template <int LP, int C>
__device__ __forceinline__ void preloadRow(int k0, int tid,
                                           const float4* __restrict__ Q4,
                                           float (&r11)[kCMax], float (&r01)[kCMax],
                                           float (&r10)[kCMax]) {
    constexpr int P = 1 << LP;
    const int i = tid >> LP;
    const int l = tid & (P - 1);
    const int mlo = l * C;
    const int mstart = mlo ? mlo : 1;
    const bool act = i < (kN - k0);
#pragma unroll
    for (int c = 0; c < C; ++c) {
        const int m = mstart + c;
        if (act && (m < mlo + C) && (m <= k0 - 2)) {
            const float4 d = Q4[colBaseD(i + m) + i];  // quad(i, i+m), immutable
            r11[c] = d.y; r01[c] = d.z; r10[c] = d.w;
        }
    }
}

template <int LP, int C>
__device__ __forceinline__ void doStepC(int k, int tid, int laneId,
                                        float4* __restrict__ Q4,
                                        uint32_t* __restrict__ wsBT,
                                        const float* __restrict__ v,
                                        int& ci, int& cj, bool& cact,
                                        float& vL, float& vR,
                                        float (&r11)[kCMax], float (&r01)[kCMax],
                                        float (&r10)[kCMax]) {
    constexpr int P = 1 << LP;
    const int i = ci, j = cj;
    const bool act = cact;
    const float vLc = vL, vRc = vR;  // prefetch below overwrites vL/vR
    const int l = tid & (P - 1);
    const int mlo = l * C;
    const int mstart = mlo ? mlo : 1;
    const int mhi = (mlo + C < k) ? (mlo + C) : k;
    const bool waveActive = (((tid & ~63) >> LP) < (kN - k));  // wave-uniform

    float bmax = -3.0e38f, v01 = -3.0e38f, v11 = -3.0e38f;
    int ib = 0x7FFFFFFF, i01 = 0x7FFFFFFF, i11 = 0x7FFFFFFF;

    // Fresh row quad (i, i+k-1): written last step, owned by exactly one lane.
    const int mf = k - 1;
    float4 fresh = make_float4(kNeg, kNeg, kNeg, kNeg);
    if (act && (mf >= mstart) && (mf < mlo + C)) {
        fresh = Q4[colBaseD(i + mf) + i];
    }

    const bool lact = waveActive && act && (mstart < mhi);
    const int qjb = colBaseD(j);
    float4 cur = make_float4(0.f, 0.f, 0.f, 0.f);
    if (lact) cur = Q4[qjb + i + mstart];  // column seed quad(i+mstart, j)
    if (act && mlo == 0) {
        bmax = cur.z; ib = 0;  // base(0) = 0 + s01[i+1][j]
        const float p00 = (cur.z + vLc) + kArcBonus;
        v01 = (p00 > kThresh) ? p00 : kNeg; i01 = 0;  // part00 seed
    }
#pragma unroll
    for (int c = 0; c < C; ++c) {
        const int m = mstart + c;
        // Row operands: registers, except the fresh quad at m == k-1 (commit it).
        const bool isF = (m == mf);
        const float a11 = isF ? fresh.y : r11[c];
        const float a01 = isF ? fresh.z : r01[c];
        const float a10 = isF ? fresh.w : r10[c];
        r11[c] = a11; r01[c] = a01; r10[c] = a10;
        const bool on = lact && (m < mhi);
        if (on) {
            const float4 nxt = Q4[qjb + i + m + 1];  // quad(q+1, j); compile-time offset
            const float base = a11 + nxt.z;          // s11[i][q] + s01[q+1][j]
            const float p01v = a01 + cur.x;          // s01[i][q] + s00[q][j]
            const float p11v = a10 + cur.y;          // s10[i][q] + s11[q][j]
            if (base > bmax) { bmax = base; ib = m; }  // strict > keeps earliest m
            if (p01v > v01) { v01 = p01v; i01 = m; }
            if (p11v > v11) { v11 = p11v; i11 = m; }
            cur = nxt;
        }
    }

    // Prefetch next step's mapping + vL/vR (overlaps reduction + barrier).
    if (k + 1 < kN) {
        mapStatic(k + 1, tid, ci, cj, cact);
        vL = cact ? v[cj * kN + ci] : 0.f;
        vR = cact ? v[ci * kN + cj] : 0.f;
    }

    if (waveActive) {
        // compile-time butterfly: xor1, xor2, mirror8 [, mirror16][, xor16][, xor32]
        float gB = dppMax<0x141>(dppMax<0x4E>(dppMax<0xB1>(bmax)));
        float g01 = dppMax<0x141>(dppMax<0x4E>(dppMax<0xB1>(v01)));
        float g11 = dppMax<0x141>(dppMax<0x4E>(dppMax<0xB1>(v11)));
        if constexpr (P >= 16) {
            gB = dppMax<0x140>(gB); g01 = dppMax<0x140>(g01); g11 = dppMax<0x140>(g11);
        }
        if constexpr (P >= 32) {
            gB = swzMax16(gB); g01 = swzMax16(g01); g11 = swzMax16(g11);
        }
        if constexpr (P == 64) {
            gB = fmaxf(gB, __shfl_xor(gB, 32, 64));
            g01 = fmaxf(g01, __shfl_xor(g01, 32, 64));
            g11 = fmaxf(g11, __shfl_xor(g11, 32, 64));
        }
        // earliest-m via ballot (contiguous chunks => lane order == m order;
        // empty lanes hold -3e38, can never equal group max)
        const int grpStart = laneId & ~(P - 1);
        const uint64_t gmask =
            (P == 64) ? ~0ull : (((1ull << P) - 1ull) << grpStart);
        const uint64_t mB = __ballot(bmax == gB) & gmask;
        const uint64_t m2 = __ballot(v01 == g01) & gmask;
        const uint64_t m3 = __ballot(v11 == g11) & gmask;
        const int rB = __shfl(ib, __ffsll((unsigned long long)mB) - 1, 64);
        const int rq01 = __shfl(i01, __ffsll((unsigned long long)m2) - 1, 64);
        const int rq11 = __shfl(i11, __ffsll((unsigned long long)m3) - 1, 64);
        if (act && l == 0) {
            writeCell(Q4, wsBT, i, j, k, gB, rB, vLc, vRc, g01, rq01, g11, rq11);
        }
    }
}

__global__ __launch_bounds__(kThreads) void eisner_dp(
    const float* __restrict__ vinfo,  // [B][N][N] fp32
    float* __restrict__ outS,         // [B][N][N][2][2] fp32 scores
    float* __restrict__ outBT,        // [B][N][N][2][2] fp32 backtrace (integer-valued)
    uint32_t* __restrict__ btPacked)  // [B][kTri] packed backtrace bytes (d_ws)
{
    extern __shared__ float4 Q4[];

    const int tid = threadIdx.x;
    const int laneId = tid & 63;
    const int b = blockIdx.x;
    const float* v = vinfo + (size_t)b * kN * kN;
    uint32_t* wsBT = btPacked + (size_t)b * kTri;

    // Diagonal quads = 0. Off-diagonal cells need no init (written before read).
    const float4 zeroq = make_float4(0.f, 0.f, 0.f, 0.f);
    if (tid < kN) Q4[colBaseD(tid) + tid] = zeroq;

    // Row caches (registers); slots overwritten per phase by preloadRow + fresh.
    float r11[kCMax], r01[kCMax], r10[kCMax];
#pragma unroll
    for (int c = 0; c < kCMax; ++c) { r11[c] = kNeg; r01[c] = kNeg; r10[c] = kNeg; }

    // Prefetch step-1 mapping + vL/vR.
    int ci, cj; bool cact;
    mapStatic(1, tid, ci, cj, cact);
    float vL = cact ? v[cj * kN + ci] : 0.f;
    float vR = cact ? v[ci * kN + cj] : 0.f;
    __syncthreads();

    for (int k = 1; k <= 16; ++k) {
        doStepSerial(k, tid, Q4, wsBT, v, ci, cj, cact, vL, vR);
        ldsBarrier();
    }
    // P=8 phase split: C=5 while k<40 (8*5=40 >= 39), C=9 after (8*9=72 >= 63),
    // so early steps don't pay 9 masked iterations. Odd C => conflict-free cols.
    preloadRow<3, 5>(17, tid, Q4, r11, r01, r10);
    for (int k = 17; k < 40; ++k) {
        doStepC<3, 5>(k, tid, laneId, Q4, wsBT, v, ci, cj, cact, vL, vR, r11, r01, r10);
        ldsBarrier();
    }
    preloadRow<3, 9>(40, tid, Q4, r11, r01, r10);
    for (int k = 40; k < 64; ++k) {
        doStepC<3, 9>(k, tid, laneId, Q4, wsBT, v, ci, cj, cact, vL, vR, r11, r01, r10);
        ldsBarrier();
    }
    preloadRow<4, 7>(64, tid, Q4, r11, r01, r10);  // 16*7=112 >= 95
    for (int k = 64; k < 96; ++k) {
        doStepC<4, 7>(k, tid, laneId, Q4, wsBT, v, ci, cj, cact, vL, vR, r11, r01, r10);
        ldsBarrier();
    }
    preloadRow<5, 5>(96, tid, Q4, r11, r01, r10);  // 32*5=160 >= 111
    for (int k = 96; k < 112; ++k) {
        doStepC<5, 5>(k, tid, laneId, Q4, wsBT, v, ci, cj, cact, vL, vR, r11, r01, r10);
        ldsBarrier();
    }
    preloadRow<6, 3>(112, tid, Q4, r11, r01, r10);  // 64*3=192 >= 127
    for (int k = 112; k < 128; ++k) {
        doStepC<6, 3>(k, tid, laneId, Q4, wsBT, v, ci, cj, cact, vL, vR, r11, r01, r10);
        ldsBarrier();
    }

    // Full barrier (drains vmcnt) before reading wsBT back.
    __syncthreads();

    // ---- epilogue: emit full [N][N][2][2] scores + backtrace, coalesced ----
    float4* gS4 = (float4*)(outS + (size_t)b * kN * kN * 4);
    float4* gB4 = (float4*)(outBT + (size_t)b * kN * kN * 4);
    const float4 negq = make_float4(kNeg, kNeg, kNeg, kNeg);
    for (int c = tid; c < kN * kN; c += kThreads) {
        const int i = c >> 7, j = c & (kN - 1);
        if (i < j) {
            const float4 q = Q4[colBaseD(j) + i];
            gS4[c] = make_float4(q.x, q.z, q.w, q.y);  // {s00, s01, s10, s11}
            const uint32_t p = wsBT[rowBase(i) + (j - i - 1)];
            gB4[c] = make_float4((float)(p & 255u), (float)((p >> 8) & 255u),
                                 (float)((p >> 16) & 255u), (float)(p >> 24));
        } else if (i == j) {
            gS4[c] = zeroq;
            gB4[c] = zeroq;
        } else {
            gS4[c] = negq;
            gB4[c] = zeroq;
        }
    }
}

extern "C" void kernel_launch(void* const* d_in, const int* in_sizes, int n_in,
                              void* d_out, int out_size, void* d_ws, size_t ws_size,
                              hipStream_t stream) {
    (void)n_in; (void)out_size; (void)ws_size;
    const float* vinfo = (const float*)d_in[0];  // fp32 [B][N][N]
    const int B = in_sizes[1];                   // b_buffer_size has B elements
    float* outS = (float*)d_out;
    float* outBT = outS + (size_t)B * kN * kN * 4;
    uint32_t* btPacked = (uint32_t*)d_ws;        // needs B*kTri*4 = ~2.1 MB

    hipFuncSetAttribute(reinterpret_cast<const void*>(eisner_dp),
                        hipFuncAttributeMaxDynamicSharedMemorySize, kDynLds);

    eisner_dp<<<dim3(B), dim3(kThreads), kDynLds, stream>>>(vinfo, outS, outBT, btPacked);
}